// Round 2
// baseline (140.548 us; speedup 1.0000x reference)
//
#include <hip/hip_runtime.h>
#include <math.h>

#define BB 4
#define CC 64
#define NN 16384   // 128*128
#define HEADS 8
#define INNER 512

// ---------------- Kernel 1: partial Gram G_b = X_b X_b^T ----------------
// grid (nslice, BB); each slice covers NN/nslice columns, processed in 64-col tiles.
__global__ __launch_bounds__(256) void k_gram(const float* __restrict__ x,
                                              float* __restrict__ part,
                                              int nslice) {
    const int s = blockIdx.x, b = blockIdx.y;
    const int t = threadIdx.x;
    const int g = t >> 6;          // wave 0..3 (splits n)
    const int lane = t & 63;
    const int ti = lane >> 3, tj = lane & 7;
    __shared__ float xs[64][65];
    float acc[8][8];
#pragma unroll
    for (int i = 0; i < 8; i++)
#pragma unroll
        for (int j = 0; j < 8; j++) acc[i][j] = 0.f;

    const float* xb = x + (size_t)b * CC * NN;
    const int cols = NN / nslice;
    const int ntiles = cols >> 6;
    const int nbase = s * cols;
    for (int tile = 0; tile < ntiles; ++tile) {
        const int n0 = nbase + tile * 64;
#pragma unroll
        for (int k = 0; k < 4; k++) {
            int f = k * 256 + t;
            int c = f >> 4, j4 = f & 15;
            const float4 v = *reinterpret_cast<const float4*>(xb + (size_t)c * NN + n0 + j4 * 4);
            xs[c][j4 * 4 + 0] = v.x; xs[c][j4 * 4 + 1] = v.y;
            xs[c][j4 * 4 + 2] = v.z; xs[c][j4 * 4 + 3] = v.w;
        }
        __syncthreads();
#pragma unroll
        for (int nn = 0; nn < 16; ++nn) {
            const int n = g * 16 + nn;
            float a[8], bv[8];
#pragma unroll
            for (int i = 0; i < 8; i++) a[i] = xs[ti * 8 + i][n];
#pragma unroll
            for (int j = 0; j < 8; j++) bv[j] = xs[tj * 8 + j][n];
#pragma unroll
            for (int i = 0; i < 8; i++)
#pragma unroll
                for (int j = 0; j < 8; j++)
                    acc[i][j] = fmaf(a[i], bv[j], acc[i][j]);
        }
        __syncthreads();
    }
    // cross-wave reduction through LDS
    for (int gg = 0; gg < 4; ++gg) {
        if (g == gg) {
#pragma unroll
            for (int i = 0; i < 8; i++)
#pragma unroll
                for (int j = 0; j < 8; j++) {
                    if (gg == 0) xs[ti * 8 + i][tj * 8 + j] = acc[i][j];
                    else         xs[ti * 8 + i][tj * 8 + j] += acc[i][j];
                }
        }
        __syncthreads();
    }
    float* p = part + (size_t)(b * nslice + s) * 4096;
#pragma unroll
    for (int k = 0; k < 16; k++) {
        int f = k * 256 + t;
        p[f] = xs[f >> 6][f & 63];
    }
}

// ---------------- Kernel 2a: reduce Gram partials ----------------
__global__ __launch_bounds__(256) void k_redG(const float* __restrict__ part,
                                              float* __restrict__ G,
                                              int nslice) {
    const int b = blockIdx.y;
    const int idx = blockIdx.x * 256 + threadIdx.x;
    const float* p = part + (size_t)b * nslice * 4096 + idx;
    float s0 = 0.f, s1 = 0.f, s2 = 0.f, s3 = 0.f;
    for (int s = 0; s < nslice; s += 4) {
        s0 += p[(size_t)s * 4096];
        s1 += p[(size_t)(s + 1) * 4096];
        s2 += p[(size_t)(s + 2) * 4096];
        s3 += p[(size_t)(s + 3) * 4096];
    }
    G[(size_t)b * 4096 + idx] = (s0 + s1) + (s2 + s3);
}

// ---------------- Kernel 2b: per-(b,h) attention + effective V weights ----------------
__global__ __launch_bounds__(256) void k_attn(const float* __restrict__ G,
                                              const float* __restrict__ Wq,
                                              const float* __restrict__ Wk,
                                              const float* __restrict__ Wv,
                                              const float* __restrict__ rescale,
                                              float* __restrict__ attn_out,
                                              float* __restrict__ wveff) {
    const int bh = blockIdx.x;
    const int b = bh >> 3, h = bh & 7;
    const int t = threadIdx.x;
    const int ti = t >> 4, tj = t & 15;
    __shared__ float Gs[64][65], Ws[64][65], Ts[64][65];
    __shared__ float qn[64], kn[64];

    for (int k = 0; k < 16; k++) { int f = k * 256 + t; Gs[f >> 6][f & 63] = G[(size_t)b * 4096 + f]; }
    for (int k = 0; k < 16; k++) { int f = k * 256 + t; int c = f >> 6, e = f & 63;
        Ws[c][e] = Wq[(size_t)c * INNER + h * 64 + e]; }
    __syncthreads();

    // Tq = G @ Wq_h
    {
        float acc[4][4] = {};
        for (int c2 = 0; c2 < 64; c2++) {
            float a[4], bv[4];
#pragma unroll
            for (int i = 0; i < 4; i++) a[i] = Gs[ti * 4 + i][c2];
#pragma unroll
            for (int j = 0; j < 4; j++) bv[j] = Ws[c2][tj * 4 + j];
#pragma unroll
            for (int i = 0; i < 4; i++)
#pragma unroll
                for (int j = 0; j < 4; j++) acc[i][j] = fmaf(a[i], bv[j], acc[i][j]);
        }
#pragma unroll
        for (int i = 0; i < 4; i++)
#pragma unroll
            for (int j = 0; j < 4; j++) Ts[ti * 4 + i][tj * 4 + j] = acc[i][j];
    }
    __syncthreads();
    if (t < 64) {
        float s = 0.f;
        for (int c = 0; c < 64; c++) s += Ws[c][t] * Ts[c][t];
        qn[t] = fmaxf(sqrtf(s), 1e-12f);
    }
    __syncthreads();
    for (int k = 0; k < 16; k++) { int f = k * 256 + t; int c = f >> 6, e = f & 63;
        Ws[c][e] = Wk[(size_t)c * INNER + h * 64 + e]; }
    __syncthreads();

    // S = Wk_h^T @ Tq   (d = ti*4+i, e = tj*4+j)
    float S[4][4] = {};
    for (int c = 0; c < 64; c++) {
        float a[4], bv[4];
#pragma unroll
        for (int i = 0; i < 4; i++) a[i] = Ws[c][ti * 4 + i];
#pragma unroll
        for (int j = 0; j < 4; j++) bv[j] = Ts[c][tj * 4 + j];
#pragma unroll
        for (int i = 0; i < 4; i++)
#pragma unroll
            for (int j = 0; j < 4; j++) S[i][j] = fmaf(a[i], bv[j], S[i][j]);
    }
    __syncthreads();

    // Tk = G @ Wk_h  (overwrites Ts)
    {
        float acc[4][4] = {};
        for (int c2 = 0; c2 < 64; c2++) {
            float a[4], bv[4];
#pragma unroll
            for (int i = 0; i < 4; i++) a[i] = Gs[ti * 4 + i][c2];
#pragma unroll
            for (int j = 0; j < 4; j++) bv[j] = Ws[c2][tj * 4 + j];
#pragma unroll
            for (int i = 0; i < 4; i++)
#pragma unroll
                for (int j = 0; j < 4; j++) acc[i][j] = fmaf(a[i], bv[j], acc[i][j]);
        }
        __syncthreads();
#pragma unroll
        for (int i = 0; i < 4; i++)
#pragma unroll
            for (int j = 0; j < 4; j++) Ts[ti * 4 + i][tj * 4 + j] = acc[i][j];
    }
    __syncthreads();
    if (t < 64) {
        float s = 0.f;
        for (int c = 0; c < 64; c++) s += Ws[c][t] * Ts[c][t];
        kn[t] = fmaxf(sqrtf(s), 1e-12f);
    }
    __syncthreads();

    // logits + softmax over e
    const float resc = rescale[h];
    float qinv[4];
#pragma unroll
    for (int j = 0; j < 4; j++) qinv[j] = 1.f / qn[tj * 4 + j];
    float p[4][4];
#pragma unroll
    for (int i = 0; i < 4; i++) {
        const float ki = resc / kn[ti * 4 + i];
        float m = -3.402823466e+38f;
#pragma unroll
        for (int j = 0; j < 4; j++) {
            float L = S[i][j] * ki * qinv[j];
            p[i][j] = L;
            m = fmaxf(m, L);
        }
        for (int o = 1; o < 16; o <<= 1) m = fmaxf(m, __shfl_xor(m, o, 64));
        float ssum = 0.f;
#pragma unroll
        for (int j = 0; j < 4; j++) { p[i][j] = expf(p[i][j] - m); ssum += p[i][j]; }
        for (int o = 1; o < 16; o <<= 1) ssum += __shfl_xor(ssum, o, 64);
        const float inv = 1.f / ssum;
#pragma unroll
        for (int j = 0; j < 4; j++) p[i][j] *= inv;
    }

    // write attn output, and stash attn into Gs (G no longer needed)
    float* ao = attn_out + (size_t)bh * 64 * 64;
#pragma unroll
    for (int i = 0; i < 4; i++) {
        float4 v; v.x = p[i][0]; v.y = p[i][1]; v.z = p[i][2]; v.w = p[i][3];
        *reinterpret_cast<float4*>(ao + (size_t)(ti * 4 + i) * 64 + tj * 4) = v;
#pragma unroll
        for (int j = 0; j < 4; j++) Gs[ti * 4 + i][tj * 4 + j] = p[i][j];
    }
    __syncthreads();
    for (int k = 0; k < 16; k++) { int f = k * 256 + t; int c = f >> 6, e = f & 63;
        Ws[c][e] = Wv[(size_t)c * INNER + h * 64 + e]; }
    __syncthreads();

    // Wveff[c][d] = sum_e Wv[c][e] * attn[d][e]
    {
        float acc[4][4] = {};
        for (int e = 0; e < 64; e++) {
            float a[4], bv[4];
#pragma unroll
            for (int i = 0; i < 4; i++) a[i] = Ws[ti * 4 + i][e];
#pragma unroll
            for (int j = 0; j < 4; j++) bv[j] = Gs[tj * 4 + j][e];
#pragma unroll
            for (int i = 0; i < 4; i++)
#pragma unroll
                for (int j = 0; j < 4; j++) acc[i][j] = fmaf(a[i], bv[j], acc[i][j]);
        }
        float* wvp = wveff + (size_t)b * CC * INNER;
#pragma unroll
        for (int i = 0; i < 4; i++) {
            float4 v; v.x = acc[i][0]; v.y = acc[i][1]; v.z = acc[i][2]; v.w = acc[i][3];
            *reinterpret_cast<float4*>(wvp + (size_t)(ti * 4 + i) * INNER + h * 64 + tj * 4) = v;
        }
    }
}

// ---------------- Kernel 2c: M partials = Wveff @ Wp ----------------
__global__ __launch_bounds__(256) void k_mpart(const float* __restrict__ wveff,
                                               const float* __restrict__ Wp,
                                               float* __restrict__ mpart) {
    const int cg = blockIdx.x, b = blockIdx.y;
    const int t = threadIdx.x, ti = t >> 4, tj = t & 15;
    __shared__ float Vs[64][65], Ps[64][65];
    float acc[4][4] = {};
    for (int sub = 0; sub < 2; ++sub) {
        const int hd0 = cg * 128 + sub * 64;
#pragma unroll
        for (int k = 0; k < 4; k++) {
            int f = k * 256 + t; int c = f >> 4, k4 = f & 15;
            float4 v = *reinterpret_cast<const float4*>(wveff + (size_t)b * CC * INNER + (size_t)c * INNER + hd0 + k4 * 4);
            Vs[c][k4 * 4 + 0] = v.x; Vs[c][k4 * 4 + 1] = v.y; Vs[c][k4 * 4 + 2] = v.z; Vs[c][k4 * 4 + 3] = v.w;
            float4 w = *reinterpret_cast<const float4*>(Wp + (size_t)(hd0 + c) * 64 + k4 * 4);
            Ps[c][k4 * 4 + 0] = w.x; Ps[c][k4 * 4 + 1] = w.y; Ps[c][k4 * 4 + 2] = w.z; Ps[c][k4 * 4 + 3] = w.w;
        }
        __syncthreads();
        for (int k = 0; k < 64; k++) {
            float a[4], bv[4];
#pragma unroll
            for (int i = 0; i < 4; i++) a[i] = Vs[ti * 4 + i][k];
#pragma unroll
            for (int j = 0; j < 4; j++) bv[j] = Ps[k][tj * 4 + j];
#pragma unroll
            for (int i = 0; i < 4; i++)
#pragma unroll
                for (int j = 0; j < 4; j++) acc[i][j] = fmaf(a[i], bv[j], acc[i][j]);
        }
        __syncthreads();
    }
    float* mp = mpart + (size_t)(b * 4 + cg) * 4096;
#pragma unroll
    for (int i = 0; i < 4; i++)
#pragma unroll
        for (int j = 0; j < 4; j++) mp[(ti * 4 + i) * 64 + tj * 4 + j] = acc[i][j];
}

// ---------------- Kernel 3: out = M^T X + bp ----------------
__global__ __launch_bounds__(256) void k_out(const float* __restrict__ x,
                                             const float* __restrict__ mpart,
                                             const float* __restrict__ bp,
                                             float* __restrict__ out) {
    const int sn = blockIdx.x, b = blockIdx.y;
    const int t = threadIdx.x, ti = t >> 4, tj = t & 15;
    __shared__ float Ms[64][65], xs[64][65];
    const float* mp = mpart + (size_t)b * 4 * 4096;
#pragma unroll
    for (int k = 0; k < 16; k++) {
        int f = k * 256 + t;
        float s = mp[f] + mp[4096 + f] + mp[2 * 4096 + f] + mp[3 * 4096 + f];
        Ms[f >> 6][f & 63] = s;
    }
    const int n0 = sn * 64;
    const float* xb = x + (size_t)b * CC * NN;
#pragma unroll
    for (int k = 0; k < 4; k++) {
        int f = k * 256 + t; int c = f >> 4, j4 = f & 15;
        float4 v = *reinterpret_cast<const float4*>(xb + (size_t)c * NN + n0 + j4 * 4);
        xs[c][j4 * 4 + 0] = v.x; xs[c][j4 * 4 + 1] = v.y;
        xs[c][j4 * 4 + 2] = v.z; xs[c][j4 * 4 + 3] = v.w;
    }
    __syncthreads();
    float acc[4][4];
#pragma unroll
    for (int i = 0; i < 4; i++) {
        const float bv = bp[ti * 4 + i];
#pragma unroll
        for (int j = 0; j < 4; j++) acc[i][j] = bv;
    }
    for (int c = 0; c < 64; c++) {
        float m[4], xv[4];
#pragma unroll
        for (int i = 0; i < 4; i++) m[i] = Ms[c][ti * 4 + i];
#pragma unroll
        for (int j = 0; j < 4; j++) xv[j] = xs[c][tj * 4 + j];
#pragma unroll
        for (int i = 0; i < 4; i++)
#pragma unroll
            for (int j = 0; j < 4; j++) acc[i][j] = fmaf(m[i], xv[j], acc[i][j]);
    }
    float* ob = out + (size_t)b * CC * NN;
#pragma unroll
    for (int i = 0; i < 4; i++) {
        float4 v; v.x = acc[i][0]; v.y = acc[i][1]; v.z = acc[i][2]; v.w = acc[i][3];
        *reinterpret_cast<float4*>(ob + (size_t)(ti * 4 + i) * NN + n0 + tj * 4) = v;
    }
}

extern "C" void kernel_launch(void* const* d_in, const int* in_sizes, int n_in,
                              void* d_out, int out_size, void* d_ws, size_t ws_size,
                              hipStream_t stream) {
    const float* x  = (const float*)d_in[0];
    const float* Wq = (const float*)d_in[1];
    const float* Wk = (const float*)d_in[2];
    const float* Wv = (const float*)d_in[3];
    const float* Wp = (const float*)d_in[4];
    const float* bp = (const float*)d_in[5];
    const float* rescale = (const float*)d_in[6];
    float* out = (float*)d_out;
    float* attn_out = out + (size_t)BB * CC * NN;  // [B][H][64][64] after the main output
    float* ws = (float*)d_ws;

    // pick the largest slice count whose workspace fits ws_size
    const size_t fixed_floats = (size_t)BB * 4096        // G
                              + (size_t)BB * CC * INNER  // wveff
                              + (size_t)BB * 4 * 4096;   // mpart
    int nslice = 64;
    while (nslice > 4 &&
           ((size_t)BB * nslice * 4096 + fixed_floats) * sizeof(float) > ws_size)
        nslice >>= 1;

    float* part  = ws;
    float* G     = part + (size_t)BB * nslice * 4096;
    float* wveff = G + (size_t)BB * 4096;
    float* mpart = wveff + (size_t)BB * CC * INNER;

    hipLaunchKernelGGL(k_gram,  dim3(nslice, BB), dim3(256), 0, stream, x, part, nslice);
    hipLaunchKernelGGL(k_redG,  dim3(16, BB),     dim3(256), 0, stream, part, G, nslice);
    hipLaunchKernelGGL(k_attn,  dim3(BB * HEADS), dim3(256), 0, stream, G, Wq, Wk, Wv, rescale, attn_out, wveff);
    hipLaunchKernelGGL(k_mpart, dim3(4, BB),      dim3(256), 0, stream, wveff, Wp, mpart);
    hipLaunchKernelGGL(k_out,   dim3(NN / 64, BB), dim3(256), 0, stream, x, mpart, bp, out);
}

// Round 4
// 137.610 us; speedup vs baseline: 1.0213x; 1.0213x over previous
//
#include <hip/hip_runtime.h>
#include <math.h>

#define BB 4
#define CC 64
#define NN 16384   // 128*128
#define HEADS 8
#define INNER 512

// ---------------- Kernel 1: partial Gram G_b = X_b X_b^T ----------------
// grid (nslice, BB), 256 threads. Each wave owns a 16-row strip of the 64x64
// output over all 64 staged columns -> no cross-wave reduction needed.
__global__ __launch_bounds__(256) void k_gram(const float* __restrict__ x,
                                              float* __restrict__ part,
                                              int nslice) {
    const int s = blockIdx.x, b = blockIdx.y;
    const int t = threadIdx.x;
    const int g = t >> 6, lane = t & 63;
    const int rg = lane >> 4;              // 0..3
    const int r0 = g * 16 + rg * 4;        // output row block (c-dim)
    const int c0 = (lane & 15) * 4;        // output col block (c-dim)
    __shared__ float xs[64][68];           // [n][c], 272B rows (16B aligned)
    float acc[4][4];
#pragma unroll
    for (int i = 0; i < 4; i++)
#pragma unroll
        for (int j = 0; j < 4; j++) acc[i][j] = 0.f;

    const float* xb = x + (size_t)b * CC * NN;
    const int cols = NN / nslice;
    const int ntiles = cols >> 6;
    const int nbase = s * cols;
    for (int tile = 0; tile < ntiles; ++tile) {
        const int n0 = nbase + tile * 64;
#pragma unroll
        for (int k = 0; k < 4; k++) {
            int f = k * 256 + t;
            int c = f >> 4, j4 = f & 15;
            const float4 v = *reinterpret_cast<const float4*>(xb + (size_t)c * NN + n0 + j4 * 4);
            xs[j4 * 4 + 0][c] = v.x; xs[j4 * 4 + 1][c] = v.y;
            xs[j4 * 4 + 2][c] = v.z; xs[j4 * 4 + 3][c] = v.w;
        }
        __syncthreads();
#pragma unroll 8
        for (int n = 0; n < 64; ++n) {
            const float4 a4 = *reinterpret_cast<const float4*>(&xs[n][r0]);
            const float4 b4 = *reinterpret_cast<const float4*>(&xs[n][c0]);
            acc[0][0] = fmaf(a4.x, b4.x, acc[0][0]); acc[0][1] = fmaf(a4.x, b4.y, acc[0][1]);
            acc[0][2] = fmaf(a4.x, b4.z, acc[0][2]); acc[0][3] = fmaf(a4.x, b4.w, acc[0][3]);
            acc[1][0] = fmaf(a4.y, b4.x, acc[1][0]); acc[1][1] = fmaf(a4.y, b4.y, acc[1][1]);
            acc[1][2] = fmaf(a4.y, b4.z, acc[1][2]); acc[1][3] = fmaf(a4.y, b4.w, acc[1][3]);
            acc[2][0] = fmaf(a4.z, b4.x, acc[2][0]); acc[2][1] = fmaf(a4.z, b4.y, acc[2][1]);
            acc[2][2] = fmaf(a4.z, b4.z, acc[2][2]); acc[2][3] = fmaf(a4.z, b4.w, acc[2][3]);
            acc[3][0] = fmaf(a4.w, b4.x, acc[3][0]); acc[3][1] = fmaf(a4.w, b4.y, acc[3][1]);
            acc[3][2] = fmaf(a4.w, b4.z, acc[3][2]); acc[3][3] = fmaf(a4.w, b4.w, acc[3][3]);
        }
        __syncthreads();
    }
    float* p = part + (size_t)(b * nslice + s) * 4096;
#pragma unroll
    for (int i = 0; i < 4; i++) {
        float4 v; v.x = acc[i][0]; v.y = acc[i][1]; v.z = acc[i][2]; v.w = acc[i][3];
        *reinterpret_cast<float4*>(p + (r0 + i) * 64 + c0) = v;
    }
}

// ---------------- Kernel 2a: reduce Gram partials ----------------
__global__ __launch_bounds__(256) void k_redG(const float* __restrict__ part,
                                              float* __restrict__ G,
                                              int nslice) {
    const int b = blockIdx.y;
    const int idx = blockIdx.x * 256 + threadIdx.x;
    const float* p = part + (size_t)b * nslice * 4096 + idx;
    float s0 = 0.f, s1 = 0.f, s2 = 0.f, s3 = 0.f;
    for (int s = 0; s < nslice; s += 4) {
        s0 += p[(size_t)s * 4096];
        s1 += p[(size_t)(s + 1) * 4096];
        s2 += p[(size_t)(s + 2) * 4096];
        s3 += p[(size_t)(s + 3) * 4096];
    }
    G[(size_t)b * 4096 + idx] = (s0 + s1) + (s2 + s3);
}

// ---------------- Kernel 2b: per-(b,h) attention, Wveff, and M (atomic) ----
__global__ __launch_bounds__(256) void k_attn(const float* __restrict__ G,
                                              const float* __restrict__ Wq,
                                              const float* __restrict__ Wk,
                                              const float* __restrict__ Wv,
                                              const float* __restrict__ Wp,
                                              const float* __restrict__ rescale,
                                              float* __restrict__ attn_out,
                                              float* __restrict__ Mg) {
    const int bh = blockIdx.x;
    const int b = bh >> 3, h = bh & 7;
    const int t = threadIdx.x;
    const int ti = t >> 4, tj = t & 15;
    __shared__ float Gs[64][68], Ws[64][68], Ts[64][68];
    __shared__ float qn[64], kn[64];

    for (int k = 0; k < 16; k++) { int f = k * 256 + t; Gs[f >> 6][f & 63] = G[(size_t)b * 4096 + f]; }
    for (int k = 0; k < 16; k++) { int f = k * 256 + t; int c = f >> 6, e = f & 63;
        Ws[c][e] = Wq[(size_t)c * INNER + h * 64 + e]; }
    __syncthreads();

    // Tq[c][e] = sum_k G[c][k] Wq[k][e]  (G symmetric -> row reads)
    {
        float acc[4][4] = {};
        for (int k2 = 0; k2 < 64; k2++) {
            const float4 a4 = *reinterpret_cast<const float4*>(&Gs[k2][ti * 4]);
            const float4 b4 = *reinterpret_cast<const float4*>(&Ws[k2][tj * 4]);
            float a[4] = {a4.x, a4.y, a4.z, a4.w}, bv[4] = {b4.x, b4.y, b4.z, b4.w};
#pragma unroll
            for (int i = 0; i < 4; i++)
#pragma unroll
                for (int j = 0; j < 4; j++) acc[i][j] = fmaf(a[i], bv[j], acc[i][j]);
        }
#pragma unroll
        for (int i = 0; i < 4; i++)
#pragma unroll
            for (int j = 0; j < 4; j++) Ts[ti * 4 + i][tj * 4 + j] = acc[i][j];
    }
    __syncthreads();
    if (t < 64) {
        float s = 0.f;
        for (int c = 0; c < 64; c++) s += Ws[c][t] * Ts[c][t];
        qn[t] = fmaxf(sqrtf(s), 1e-12f);
    }
    __syncthreads();
    for (int k = 0; k < 16; k++) { int f = k * 256 + t; int c = f >> 6, e = f & 63;
        Ws[c][e] = Wk[(size_t)c * INNER + h * 64 + e]; }
    __syncthreads();

    // S[d][e] = sum_c Wk[c][d] Tq[c][e]
    float S[4][4] = {};
    for (int k2 = 0; k2 < 64; k2++) {
        const float4 a4 = *reinterpret_cast<const float4*>(&Ws[k2][ti * 4]);
        const float4 b4 = *reinterpret_cast<const float4*>(&Ts[k2][tj * 4]);
        float a[4] = {a4.x, a4.y, a4.z, a4.w}, bv[4] = {b4.x, b4.y, b4.z, b4.w};
#pragma unroll
        for (int i = 0; i < 4; i++)
#pragma unroll
            for (int j = 0; j < 4; j++) S[i][j] = fmaf(a[i], bv[j], S[i][j]);
    }

    // Tk = G @ Wk (registers), then barrier, then overwrite Ts
    {
        float acc[4][4] = {};
        for (int k2 = 0; k2 < 64; k2++) {
            const float4 a4 = *reinterpret_cast<const float4*>(&Gs[k2][ti * 4]);
            const float4 b4 = *reinterpret_cast<const float4*>(&Ws[k2][tj * 4]);
            float a[4] = {a4.x, a4.y, a4.z, a4.w}, bv[4] = {b4.x, b4.y, b4.z, b4.w};
#pragma unroll
            for (int i = 0; i < 4; i++)
#pragma unroll
                for (int j = 0; j < 4; j++) acc[i][j] = fmaf(a[i], bv[j], acc[i][j]);
        }
        __syncthreads();   // everyone done reading Ts (Tq)
#pragma unroll
        for (int i = 0; i < 4; i++)
#pragma unroll
            for (int j = 0; j < 4; j++) Ts[ti * 4 + i][tj * 4 + j] = acc[i][j];
    }
    __syncthreads();
    if (t < 64) {
        float s = 0.f;
        for (int c = 0; c < 64; c++) s += Ws[c][t] * Ts[c][t];
        kn[t] = fmaxf(sqrtf(s), 1e-12f);
    }
    __syncthreads();

    // logits + softmax over e
    const float resc = rescale[h];
    float qinv[4];
#pragma unroll
    for (int j = 0; j < 4; j++) qinv[j] = 1.f / qn[tj * 4 + j];
    float p[4][4];
#pragma unroll
    for (int i = 0; i < 4; i++) {
        const float ki = resc / kn[ti * 4 + i];
        float m = -3.402823466e+38f;
#pragma unroll
        for (int j = 0; j < 4; j++) {
            float L = S[i][j] * ki * qinv[j];
            p[i][j] = L;
            m = fmaxf(m, L);
        }
        for (int o = 1; o < 16; o <<= 1) m = fmaxf(m, __shfl_xor(m, o, 64));
        float ssum = 0.f;
#pragma unroll
        for (int j = 0; j < 4; j++) { p[i][j] = expf(p[i][j] - m); ssum += p[i][j]; }
        for (int o = 1; o < 16; o <<= 1) ssum += __shfl_xor(ssum, o, 64);
        const float inv = 1.f / ssum;
#pragma unroll
        for (int j = 0; j < 4; j++) p[i][j] *= inv;
    }

    // write attn output; stash attn TRANSPOSED into Ts: Ts[e][d]
    float* ao = attn_out + (size_t)bh * 64 * 64;
#pragma unroll
    for (int i = 0; i < 4; i++) {
        float4 v; v.x = p[i][0]; v.y = p[i][1]; v.z = p[i][2]; v.w = p[i][3];
        *reinterpret_cast<float4*>(ao + (size_t)(ti * 4 + i) * 64 + tj * 4) = v;
#pragma unroll
        for (int j = 0; j < 4; j++) Ts[tj * 4 + j][ti * 4 + i] = p[i][j];
    }
    // load Wv transposed: Ws[e][c]
    for (int k = 0; k < 16; k++) { int f = k * 256 + t; int c = f >> 6, e = f & 63;
        Ws[e][c] = Wv[(size_t)c * INNER + h * 64 + e]; }
    __syncthreads();

    // Wveff[c][d] = sum_e Wv[c][e] attn[d][e]  (both row-wise b128)
    float accv[4][4] = {};
    for (int e = 0; e < 64; e++) {
        const float4 a4 = *reinterpret_cast<const float4*>(&Ws[e][ti * 4]);
        const float4 b4 = *reinterpret_cast<const float4*>(&Ts[e][tj * 4]);
        float a[4] = {a4.x, a4.y, a4.z, a4.w}, bv[4] = {b4.x, b4.y, b4.z, b4.w};
#pragma unroll
        for (int i = 0; i < 4; i++)
#pragma unroll
            for (int j = 0; j < 4; j++) accv[i][j] = fmaf(a[i], bv[j], accv[i][j]);
    }
    __syncthreads();   // all reads of Ts(attnT)/Ws(WvT) done
    // stash Wveff transposed: Ts[d][c]; load Wp_h rows: Ws[d][c2]
#pragma unroll
    for (int i = 0; i < 4; i++)
#pragma unroll
        for (int j = 0; j < 4; j++) Ts[tj * 4 + j][ti * 4 + i] = accv[i][j];
    for (int k = 0; k < 16; k++) { int f = k * 256 + t;
        Ws[f >> 6][f & 63] = Wp[(size_t)h * 4096 + f]; }
    __syncthreads();

    // M[c][c2] += sum_d Wveff[c][d] Wp[h*64+d][c2]
    float accm[4][4] = {};
    for (int d = 0; d < 64; d++) {
        const float4 a4 = *reinterpret_cast<const float4*>(&Ts[d][ti * 4]);
        const float4 b4 = *reinterpret_cast<const float4*>(&Ws[d][tj * 4]);
        float a[4] = {a4.x, a4.y, a4.z, a4.w}, bv[4] = {b4.x, b4.y, b4.z, b4.w};
#pragma unroll
        for (int i = 0; i < 4; i++)
#pragma unroll
            for (int j = 0; j < 4; j++) accm[i][j] = fmaf(a[i], bv[j], accm[i][j]);
    }
    float* Mb = Mg + (size_t)b * 4096;
#pragma unroll
    for (int i = 0; i < 4; i++)
#pragma unroll
        for (int j = 0; j < 4; j++)
            atomicAdd(&Mb[(ti * 4 + i) * 64 + tj * 4 + j], accm[i][j]);
}

// ---------------- Kernel 3: out = M^T X + bp ----------------
__global__ __launch_bounds__(256) void k_out(const float* __restrict__ x,
                                             const float* __restrict__ Mg,
                                             const float* __restrict__ bp,
                                             float* __restrict__ out) {
    const int sn = blockIdx.x, b = blockIdx.y;
    const int t = threadIdx.x, ti = t >> 4, tj = t & 15;
    __shared__ float Ms[64][68], xs[64][68];
    for (int k = 0; k < 16; k++) { int f = k * 256 + t; Ms[f >> 6][f & 63] = Mg[(size_t)b * 4096 + f]; }
    const int n0 = sn * 64;
    const float* xb = x + (size_t)b * CC * NN;
#pragma unroll
    for (int k = 0; k < 4; k++) {
        int f = k * 256 + t; int c = f >> 4, j4 = f & 15;
        float4 v = *reinterpret_cast<const float4*>(xb + (size_t)c * NN + n0 + j4 * 4);
        xs[c][j4 * 4 + 0] = v.x; xs[c][j4 * 4 + 1] = v.y;
        xs[c][j4 * 4 + 2] = v.z; xs[c][j4 * 4 + 3] = v.w;
    }
    __syncthreads();
    float acc[4][4];
#pragma unroll
    for (int i = 0; i < 4; i++) {
        const float bv = bp[ti * 4 + i];
#pragma unroll
        for (int j = 0; j < 4; j++) acc[i][j] = bv;
    }
    for (int c = 0; c < 64; c++) {
        const float4 m4 = *reinterpret_cast<const float4*>(&Ms[c][ti * 4]);
        const float4 x4 = *reinterpret_cast<const float4*>(&xs[c][tj * 4]);
        float m[4] = {m4.x, m4.y, m4.z, m4.w}, xv[4] = {x4.x, x4.y, x4.z, x4.w};
#pragma unroll
        for (int i = 0; i < 4; i++)
#pragma unroll
            for (int j = 0; j < 4; j++) acc[i][j] = fmaf(m[i], xv[j], acc[i][j]);
    }
    float* ob = out + (size_t)b * CC * NN;
#pragma unroll
    for (int i = 0; i < 4; i++) {
        float4 v; v.x = acc[i][0]; v.y = acc[i][1]; v.z = acc[i][2]; v.w = acc[i][3];
        *reinterpret_cast<float4*>(ob + (size_t)(ti * 4 + i) * NN + n0 + tj * 4) = v;
    }
}

extern "C" void kernel_launch(void* const* d_in, const int* in_sizes, int n_in,
                              void* d_out, int out_size, void* d_ws, size_t ws_size,
                              hipStream_t stream) {
    const float* x  = (const float*)d_in[0];
    const float* Wq = (const float*)d_in[1];
    const float* Wk = (const float*)d_in[2];
    const float* Wv = (const float*)d_in[3];
    const float* Wp = (const float*)d_in[4];
    const float* bp = (const float*)d_in[5];
    const float* rescale = (const float*)d_in[6];
    float* out = (float*)d_out;
    float* attn_out = out + (size_t)BB * CC * NN;
    float* ws = (float*)d_ws;

    // pick the largest slice count whose workspace fits ws_size
    const size_t fixed_floats = (size_t)BB * 4096     // G
                              + (size_t)BB * 4096;    // M
    int nslice = 256;
    while (nslice > 4 &&
           ((size_t)BB * nslice * 4096 + fixed_floats) * sizeof(float) > ws_size)
        nslice >>= 1;

    float* part = ws;
    float* G    = part + (size_t)BB * nslice * 4096;
    float* Mg   = G + (size_t)BB * 4096;

    hipMemsetAsync(Mg, 0, (size_t)BB * 4096 * sizeof(float), stream);
    hipLaunchKernelGGL(k_gram,  dim3(nslice, BB),  dim3(256), 0, stream, x, part, nslice);
    hipLaunchKernelGGL(k_redG,  dim3(16, BB),      dim3(256), 0, stream, part, G, nslice);
    hipLaunchKernelGGL(k_attn,  dim3(BB * HEADS),  dim3(256), 0, stream, G, Wq, Wk, Wv, Wp, rescale, attn_out, Mg);
    hipLaunchKernelGGL(k_out,   dim3(NN / 64, BB), dim3(256), 0, stream, x, Mg, bp, out);
}